// Round 1
// baseline (507.598 us; speedup 1.0000x reference)
//
#include <hip/hip_runtime.h>
#include <cstdint>
#include <cstddef>

#define GAS __attribute__((address_space(1)))
#define LAS __attribute__((address_space(3)))

typedef short bf16x8 __attribute__((ext_vector_type(8)));
typedef float f32x4 __attribute__((ext_vector_type(4)));

__device__ __forceinline__ unsigned short f2bf(float f) {
    unsigned u = __float_as_uint(f);
    return (unsigned short)((u + 0x7fffu + ((u >> 16) & 1u)) >> 16);
}

__device__ __forceinline__ void async16(const void* g, void* l) {
    __builtin_amdgcn_global_load_lds((const GAS unsigned int*)g,
                                     (LAS unsigned int*)l, 16, 0, 0);
}

// ---------------------------------------------------------------------------
// Rotation tables: dA/oA/dB/oB, each [8][2048] fp32, matching the reference's
// stack+reshape scramble: flat = i*16 + l*2 + j  ->  (row, col) of [8][2048].
// ---------------------------------------------------------------------------
__global__ void build_tables(const float* __restrict__ thetaA,
                             const float* __restrict__ thetaB,
                             float* __restrict__ tabs) {
    int idx = blockIdx.x * 256 + threadIdx.x;   // 0..16383
    if (idx >= 16384) return;
    int i = idx >> 4, l = (idx >> 1) & 7, j = idx & 1;
    float th = thetaA[i * 8 + l];
    tabs[idx]         = cosf(th);
    tabs[16384 + idx] = (j ? 1.f : -1.f) * sinf(th);

    int c = idx & 2047, r = idx >> 11;
    float dB = 1.f, oB = 0.f;
    if (c >= 1 && c <= 2046) {
        int fb = r * 2046 + (c - 1);
        int ib = fb >> 4, lb = (fb >> 1) & 7, jb = fb & 1;
        float tb = thetaB[ib * 8 + lb];
        dB = cosf(tb);
        oB = (jb ? 1.f : -1.f) * sinf(tb);
    }
    tabs[32768 + idx] = dB;
    tabs[49152 + idx] = oB;
}

// ---------------------------------------------------------------------------
// Xc[b][k] (bf16, 4096x4096) = k<2048 ? input_[b][k] : hx[b][k-2048]
// ---------------------------------------------------------------------------
__global__ void cast_concat(const float* __restrict__ in0,
                            const float* __restrict__ hx,
                            unsigned short* __restrict__ Xc) {
    size_t idx = ((size_t)blockIdx.x * 256 + threadIdx.x) * 4;
    size_t row = idx >> 12;
    int c = (int)(idx & 4095);
    const float* src = (c < 2048) ? (in0 + row * 2048 + c)
                                  : (hx + row * 2048 + (c - 2048));
    float4 v = *(const float4*)src;
    ushort4 o;
    o.x = f2bf(v.x); o.y = f2bf(v.y); o.z = f2bf(v.z); o.w = f2bf(v.w);
    *(ushort4*)(Xc + idx) = o;
}

// ---------------------------------------------------------------------------
// WgT[n][k] (bf16, 4096x4096) = k<2048 ? gate_U[k][n] : gate_W[k-2048][n]
// ---------------------------------------------------------------------------
__global__ void tcast_gate(const float* __restrict__ gU,
                           const float* __restrict__ gW,
                           unsigned short* __restrict__ WT) {
    __shared__ float tile[32][33];
    int k0 = blockIdx.x * 32, n0 = blockIdx.y * 32;
    int tx = threadIdx.x, ty = threadIdx.y;   // (32, 8)
#pragma unroll
    for (int i = 0; i < 32; i += 8) {
        int k = k0 + ty + i;
        float v = (k < 2048) ? gU[(size_t)k * 4096 + n0 + tx]
                             : gW[(size_t)(k - 2048) * 4096 + n0 + tx];
        tile[ty + i][tx] = v;
    }
    __syncthreads();
#pragma unroll
    for (int i = 0; i < 32; i += 8) {
        int n = n0 + ty + i;
        WT[(size_t)n * 4096 + k0 + tx] = f2bf(tile[tx][ty + i]);
    }
}

// UT[n][k] (bf16, 2048x2048) = U[k][n]
__global__ void tcast_u(const float* __restrict__ U,
                        unsigned short* __restrict__ UT) {
    __shared__ float tile[32][33];
    int k0 = blockIdx.x * 32, n0 = blockIdx.y * 32;
    int tx = threadIdx.x, ty = threadIdx.y;
#pragma unroll
    for (int i = 0; i < 32; i += 8)
        tile[ty + i][tx] = U[(size_t)(k0 + ty + i) * 2048 + n0 + tx];
    __syncthreads();
#pragma unroll
    for (int i = 0; i < 32; i += 8)
        UT[(size_t)(n0 + ty + i) * 2048 + k0 + tx] = f2bf(tile[tx][ty + i]);
}

// ---------------------------------------------------------------------------
// EUNN scan: one block per batch row. x kept in registers (8 cols/thread);
// phase A is thread-local (adjacent pairs), phase B permutes through LDS.
// ---------------------------------------------------------------------------
__global__ void eunn_kernel(const float* __restrict__ hx,
                            const float* __restrict__ tabs,
                            float* __restrict__ E) {
    __shared__ float xs[2048];
    int b = blockIdx.x, t = threadIdx.x;   // 256 threads
    float x[8];
    const float* row = hx + (size_t)b * 2048;
#pragma unroll
    for (int e = 0; e < 8; ++e) x[e] = row[t * 8 + e];

    const float* dA = tabs;
    const float* oA = tabs + 16384;
    const float* dB = tabs + 32768;
    const float* oB = tabs + 49152;

    for (int r = 0; r < 8; ++r) {
        // phase A: x[c] = x[c]*dA + x[c^1]*oA   (pairs local to thread)
#pragma unroll
        for (int p = 0; p < 4; ++p) {
            int c0 = t * 8 + 2 * p;
            float a0 = x[2 * p], a1 = x[2 * p + 1];
            float d0 = dA[r * 2048 + c0], d1 = dA[r * 2048 + c0 + 1];
            float o0 = oA[r * 2048 + c0], o1 = oA[r * 2048 + c0 + 1];
            x[2 * p]     = a0 * d0 + a1 * o0;
            x[2 * p + 1] = a1 * d1 + a0 * o1;
        }
        // phase B: y[0]=x[0]; y[c]=x[2c] (1..1023); y[c]=x[2c-2047] (1024..2046); y[2047]=x[2047]
        __syncthreads();   // prior iteration's reads done before overwrite
#pragma unroll
        for (int e = 0; e < 8; ++e) xs[t * 8 + e] = x[e];
        __syncthreads();
#pragma unroll
        for (int e = 0; e < 8; ++e) {
            int c = t * 8 + e;
            float y;
            if (c == 0) y = xs[0];
            else if (c == 2047) y = xs[2047];
            else if (c <= 1023) y = xs[2 * c];
            else y = xs[2 * c - 2047];
            x[e] = x[e] * dB[r * 2048 + c] + y * oB[r * 2048 + c];
        }
    }
    float* out = E + (size_t)b * 2048;
#pragma unroll
    for (int e = 0; e < 8; ++e) out[t * 8 + e] = x[e];
}

// ---------------------------------------------------------------------------
// bf16 MFMA GEMM, C = A(MxK) * Bt(NxK)^T.  BM=BN=128, BK=64, 256 thr (4 waves,
// 2x2 wave grid, 64x64 per wave as 4x4 16x16 frags).  Staging uses
// global_load_lds width-16 with XOR-swizzled per-lane gather so the
// ds_read_b128 fragment reads are bank-conflict-free.
// MODE 0: C = acc + cbias[col]   (gates)
// MODE 1: fused GORU epilogue -> Out
// ---------------------------------------------------------------------------
template <int MODE>
__launch_bounds__(256)
__global__ void gemm_nt(const unsigned short* __restrict__ A, int lda,
                        const unsigned short* __restrict__ Bt, int ldb,
                        int K, int ldc,
                        float* __restrict__ C,
                        const float* __restrict__ cbias,
                        const float* __restrict__ E,
                        const float* __restrict__ gates,
                        const float* __restrict__ hx,
                        const float* __restrict__ bias,
                        float* __restrict__ Out) {
    __shared__ __align__(16) unsigned short As[128 * 64];
    __shared__ __align__(16) unsigned short Bs[128 * 64];
    const int tid = threadIdx.x;
    const int lane = tid & 63;
    const int wave = tid >> 6;
    const int row0 = blockIdx.y * 128;
    const int col0 = blockIdx.x * 128;

    // Per-lane global gather addresses for the 4 A- and 4 B-staging
    // instructions this wave issues per K-iter.  LDS chunk L holds tile chunk
    // (m = L>>3, kc = (L&7) ^ (m&7))  -- the XOR swizzle.
    const unsigned short* aP[4];
    const unsigned short* bP[4];
#pragma unroll
    for (int s = 0; s < 4; ++s) {
        int L = (wave * 4 + s) * 64 + lane;
        int m = L >> 3;
        int kc = (L & 7) ^ (m & 7);
        aP[s] = A + (size_t)(row0 + m) * lda + kc * 8;
        bP[s] = Bt + (size_t)(col0 + m) * ldb + kc * 8;
    }

    f32x4 acc[4][4];
#pragma unroll
    for (int i = 0; i < 4; ++i)
#pragma unroll
        for (int j = 0; j < 4; ++j) acc[i][j] = (f32x4)0.f;

    const int wm = wave & 1, wn = wave >> 1;
    const int r = lane & 15, quad = lane >> 4;

    const int nIter = K >> 6;
    for (int it = 0; it < nIter; ++it) {
#pragma unroll
        for (int s = 0; s < 4; ++s) {
            async16(aP[s], &As[(wave * 4 + s) * 512]);
            async16(bP[s], &Bs[(wave * 4 + s) * 512]);
            aP[s] += 64;
            bP[s] += 64;
        }
        __syncthreads();
#pragma unroll
        for (int ks = 0; ks < 2; ++ks) {
            bf16x8 af[4], bfr[4];
#pragma unroll
            for (int mt = 0; mt < 4; ++mt) {
                int m = wm * 64 + mt * 16 + r;
                int slot = (ks * 4 + quad) ^ (m & 7);
                af[mt] = *(const bf16x8*)&As[(m * 8 + slot) * 8];
            }
#pragma unroll
            for (int nt = 0; nt < 4; ++nt) {
                int n = wn * 64 + nt * 16 + r;
                int slot = (ks * 4 + quad) ^ (n & 7);
                bfr[nt] = *(const bf16x8*)&Bs[(n * 8 + slot) * 8];
            }
#pragma unroll
            for (int mt = 0; mt < 4; ++mt)
#pragma unroll
                for (int nt = 0; nt < 4; ++nt)
                    acc[mt][nt] = __builtin_amdgcn_mfma_f32_16x16x32_bf16(
                        af[mt], bfr[nt], acc[mt][nt], 0, 0, 0);
        }
        __syncthreads();
    }

    // Epilogue.  C/D frag layout: col = lane&15, row = quad*4 + reg.
#pragma unroll
    for (int mt = 0; mt < 4; ++mt) {
#pragma unroll
        for (int nt = 0; nt < 4; ++nt) {
#pragma unroll
            for (int reg = 0; reg < 4; ++reg) {
                int row = row0 + wm * 64 + mt * 16 + quad * 4 + reg;
                int col = col0 + wn * 64 + nt * 16 + r;
                float v = acc[mt][nt][reg];
                if constexpr (MODE == 0) {
                    C[(size_t)row * ldc + col] = v + cbias[col];
                } else {
                    size_t gi = (size_t)row * 4096 + col;
                    size_t oi = (size_t)row * 2048 + col;
                    float rg = gates[gi];
                    float zg = gates[gi + 2048];
                    float nh = v + E[oi] * rg;
                    float s = fmaxf(fabsf(nh) + bias[col], 0.f);
                    float sg = (nh > 0.f) ? 1.f : ((nh < 0.f) ? -1.f : 0.f);
                    nh = sg * s;
                    Out[oi] = hx[oi] * zg + (1.f - zg) * nh;
                }
            }
        }
    }
}

// ---------------------------------------------------------------------------
extern "C" void kernel_launch(void* const* d_in, const int* in_sizes, int n_in,
                              void* d_out, int out_size, void* d_ws,
                              size_t ws_size, hipStream_t stream) {
    const float* input_ = (const float*)d_in[0];
    const float* hx = (const float*)d_in[1];
    const float* U = (const float*)d_in[2];
    const float* thetaA = (const float*)d_in[3];
    const float* thetaB = (const float*)d_in[4];
    const float* bias = (const float*)d_in[5];
    const float* gate_U = (const float*)d_in[6];
    const float* gate_W = (const float*)d_in[7];
    const float* gate_bias = (const float*)d_in[8];
    float* out = (float*)d_out;

    char* ws = (char*)d_ws;
    unsigned short* Xc  = (unsigned short*)(ws);                  // 32 MB
    unsigned short* WgT = (unsigned short*)(ws + 33554432ull);    // 32 MB
    unsigned short* UT  = (unsigned short*)(ws + 67108864ull);    // 8 MB
    float* gates        = (float*)(ws + 75497472ull);             // 64 MB
    float* E            = (float*)(ws + 142606336ull);            // 32 MB
    float* tabs         = (float*)(ws + 176160768ull);            // 256 KB

    build_tables<<<64, 256, 0, stream>>>(thetaA, thetaB, tabs);
    cast_concat<<<16384, 256, 0, stream>>>(input_, hx, Xc);
    {
        dim3 g(128, 128), b(32, 8);
        tcast_gate<<<g, b, 0, stream>>>(gate_U, gate_W, WgT);
    }
    {
        dim3 g(64, 64), b(32, 8);
        tcast_u<<<g, b, 0, stream>>>(U, UT);
    }
    eunn_kernel<<<4096, 256, 0, stream>>>(hx, tabs, E);
    {
        dim3 g(32, 32);   // gates: M=4096, N=4096, K=4096
        gemm_nt<0><<<g, 256, 0, stream>>>(Xc, 4096, WgT, 4096, 4096, 4096,
                                          gates, gate_bias, nullptr, nullptr,
                                          nullptr, nullptr, nullptr);
    }
    {
        dim3 g(16, 32);   // Ux + fused epilogue: M=4096, N=2048, K=2048
        gemm_nt<1><<<g, 256, 0, stream>>>(Xc, 4096, UT, 2048, 2048, 2048,
                                          nullptr, nullptr, E, gates, hx, bias,
                                          out);
    }
}